// Round 7
// baseline (398.396 us; speedup 1.0000x reference)
//
#include <hip/hip_runtime.h>
#include <hip/hip_bf16.h>

typedef __hip_bfloat16 bf16;
typedef __bf16 bf16x8 __attribute__((ext_vector_type(8)));
typedef float  f32x4  __attribute__((ext_vector_type(4)));

#define Bq  4
#define Sq  1024
#define Dq  1024
#define Hq  16
#define DHq 64
#define NCq 8
#define NDq 4

__device__ __forceinline__ float bf2f(unsigned short u) {
    union { float f; unsigned int i; } x;
    x.i = ((unsigned int)u) << 16;
    return x.f;
}
__device__ __forceinline__ unsigned short f2bf(float f) {
    union { float f; unsigned int u; } x; x.f = f;
    unsigned int r = x.u + 0x7fffu + ((x.u >> 16) & 1u);
    return (unsigned short)(r >> 16);
}
__device__ __forceinline__ bf16x8 ld8(const bf16* p) {
    union { uint4 u; bf16x8 v; } t;
    t.u = *(const uint4*)p;
    return t.v;
}
__device__ __forceinline__ void gload16(const void* g, void* l) {
    __builtin_amdgcn_global_load_lds(
        (const __attribute__((address_space(1))) void*)g,
        (__attribute__((address_space(3))) void*)l, 16, 0, 0);
}

// ---- DPP 16-lane reductions (VALU-only, no LDS latency) ----
template<int C> __device__ __forceinline__ float dpp_f(float x) {
    return __int_as_float(__builtin_amdgcn_update_dpp(0, __float_as_int(x), C, 0xF, 0xF, true));
}
__device__ __forceinline__ float red16_max(float x) {
    x = fmaxf(x, dpp_f<0xB1>(x));    // quad_perm xor1
    x = fmaxf(x, dpp_f<0x4E>(x));    // quad_perm xor2
    x = fmaxf(x, dpp_f<0x141>(x));   // row_half_mirror
    x = fmaxf(x, dpp_f<0x140>(x));   // row_mirror
    return x;
}
__device__ __forceinline__ float red16_sum(float x) {
    x += dpp_f<0xB1>(x);
    x += dpp_f<0x4E>(x);
    x += dpp_f<0x141>(x);
    x += dpp_f<0x140>(x);
    return x;
}

// ---------------- K0: prep — fp32->bf16 converts + mask bit-pack + time vector ----------------
__global__ __launch_bounds__(256) void prep_kernel(
    const float* __restrict__ X,  bf16* __restrict__ Xb,
    const float* __restrict__ Wi, bf16* __restrict__ Wib,
    const float* __restrict__ Wo, bf16* __restrict__ Wob,
    const int* __restrict__ card, const int* __restrict__ deck,
    const float* __restrict__ td,
    unsigned int* __restrict__ cb, unsigned int* __restrict__ db,
    float* __restrict__ tv)
{
    const int blk = blockIdx.x;
    if (blk < 8192) {
        const float* src; bf16* dst; int base;
        if (blk < 4096)      { src = X;  dst = Xb;  base = blk; }
        else if (blk < 7168) { src = Wi; dst = Wib; base = blk - 4096; }
        else                 { src = Wo; dst = Wob; base = blk - 7168; }
        const size_t off = (size_t)base * 1024 + threadIdx.x * 4;
        float4 v = *(const float4*)(src + off);
        ushort4 o;
        o.x = f2bf(v.x); o.y = f2bf(v.y); o.z = f2bf(v.z); o.w = f2bf(v.w);
        *(ushort4*)(dst + off) = o;
    } else {
        const size_t idx = (size_t)(blk - 8192) * 256 + threadIdx.x;
        const bool c = card[idx] != 0;
        const bool d = deck[idx] != 0;
        unsigned long long bc = __ballot(c);
        unsigned long long bd = __ballot(d);
        const int lane = threadIdx.x & 63;
        if (lane == 0) {
            cb[idx >> 5] = (unsigned int)bc;
            db[idx >> 5] = (unsigned int)bd;
        } else if (lane == 32) {
            cb[idx >> 5] = (unsigned int)(bc >> 32);
            db[idx >> 5] = (unsigned int)(bd >> 32);
        }
        if (idx < (size_t)Bq * Sq)
            tv[idx] = td[idx * Sq];      // column 0 == t_s - t_0 (exact)
    }
}

// ---------------- K1: QKV projection, MFMA 128x128 tile ----------------
__global__ __launch_bounds__(256, 3) void gemm_qkv_mfma(
    const bf16* __restrict__ Xb, const bf16* __restrict__ Wib,
    const float* __restrict__ bias,
    bf16* __restrict__ Q, bf16* __restrict__ K, bf16* __restrict__ Vt)
{
    __shared__ __align__(16) char smem[36864];
    bf16* ldsA = (bf16*)smem;
    bf16* ldsB = (bf16*)(smem + 8192);

    const int tid  = threadIdx.x;
    const int wave = tid >> 6, lane = tid & 63;
    const int quad = lane >> 4, l16 = lane & 15;
    const int bm = blockIdx.x & 31;
    const int bn = blockIdx.x >> 5;
    const int m0 = bm * 128, n0 = bn * 128;
    const int wm = wave & 1, wn = wave >> 1;
    const int rA = lane >> 2, c8 = (lane & 3) * 8;
    const int cA0 = wave, cA1 = wave + 4;

    f32x4 acc[4][4];
    #pragma unroll
    for (int i = 0; i < 4; ++i)
        #pragma unroll
        for (int j = 0; j < 4; ++j) { acc[i][j][0]=0.f; acc[i][j][1]=0.f; acc[i][j][2]=0.f; acc[i][j][3]=0.f; }

    for (int k0 = 0; k0 < 1024; k0 += 32) {
        gload16(Xb  + (size_t)(m0 + cA0*16 + rA) * 1024 + k0 + c8, smem        + cA0*1024);
        gload16(Xb  + (size_t)(m0 + cA1*16 + rA) * 1024 + k0 + c8, smem        + cA1*1024);
        gload16(Wib + (size_t)(n0 + cA0*16 + rA) * 1024 + k0 + c8, smem + 8192 + cA0*1024);
        gload16(Wib + (size_t)(n0 + cA1*16 + rA) * 1024 + k0 + c8, smem + 8192 + cA1*1024);
        __syncthreads();
        bf16x8 af[4], bfr[4];
        #pragma unroll
        for (int i = 0; i < 4; ++i) af[i] = ld8(ldsA + (wm*64 + i*16 + l16) * 32 + quad*8);
        #pragma unroll
        for (int j = 0; j < 4; ++j) bfr[j] = ld8(ldsB + (wn*64 + j*16 + l16) * 32 + quad*8);
        #pragma unroll
        for (int i = 0; i < 4; ++i)
            #pragma unroll
            for (int j = 0; j < 4; ++j)
                acc[i][j] = __builtin_amdgcn_mfma_f32_16x16x32_bf16(af[i], bfr[j], acc[i][j], 0, 0, 0);
        __syncthreads();
    }

    const int nw  = n0 + wn * 64;
    const int sec = n0 >> 10;
    float bj[4];
    #pragma unroll
    for (int j = 0; j < 4; ++j) bj[j] = bias[nw + j*16 + l16];

    if (sec < 2) {
        #pragma unroll
        for (int i = 0; i < 4; ++i) {
            #pragma unroll
            for (int r = 0; r < 4; ++r) {
                const int m = m0 + wm*64 + i*16 + quad*4 + r;
                const int b = m >> 10, s = m & 1023;
                #pragma unroll
                for (int j = 0; j < 4; ++j) {
                    const int n = nw + j*16 + l16;
                    const int o = n & 1023;
                    const int h = o >> 6, dh = o & 63;
                    const float v = acc[i][j][r] + bj[j];
                    const size_t dst = (((size_t)(b * Hq + h)) * Sq + s) * DHq + dh;
                    if (sec == 0) Q[dst] = __float2bfloat16(v * 0.125f);
                    else          K[dst] = __float2bfloat16(v);
                }
            }
        }
    } else {
        unsigned short* Tr = (unsigned short*)(smem + wave * 9216);  // [64][72]
        #pragma unroll
        for (int i = 0; i < 4; ++i)
            #pragma unroll
            for (int j = 0; j < 4; ++j)
                #pragma unroll
                for (int r = 0; r < 4; ++r)
                    Tr[(j*16 + l16) * 72 + i*16 + quad*4 + r] = f2bf(acc[i][j][r] + bj[j]);
        __syncthreads();
        const int h  = (bn - 16) * 2 + wn;
        const int bB = m0 >> 10;
        const int s0 = (m0 & 1023) + wm * 64;
        const int r8 = lane >> 3, c16 = lane & 7;
        #pragma unroll
        for (int it = 0; it < 8; ++it) {
            const int dh = it * 8 + r8;
            uint4 u = *(const uint4*)(Tr + dh * 72 + c16 * 8);
            *(uint4*)(Vt + ((size_t)(bB * Hq + h) * DHq + dh) * Sq + s0 + c16 * 8) = u;
        }
    }
}

// ---------------- K2: MFMA flash attention — single-wave blocks (occupancy) ----------------
// Grid: B*H*(S/16) = 4096 blocks of 64 threads; one wave owns 16 query rows.
__global__ __launch_bounds__(64, 4) void attn_mfma4_kernel(
    const bf16* __restrict__ Qg, const bf16* __restrict__ Kg, const bf16* __restrict__ Vtg,
    const unsigned int* __restrict__ cb, const unsigned int* __restrict__ db,
    const float* __restrict__ tv,
    const float* __restrict__ tdw, const float* __restrict__ tdd,
    bf16* __restrict__ O)
{
    __shared__ unsigned short Pt[16][72];
    const int lane = threadIdx.x & 63;
    const int quad = lane >> 4, l16 = lane & 15;
    const int blk  = blockIdx.x;
    // swizzle: chunk slow -> all chunks of one (b,h) share blk&7 (same XCD)
    const int chunk = blk >> 6;          // 0..63 (16-row chunks)
    const int h     = (blk >> 2) & 15;
    const int b     = blk & 3;
    const int i_base = chunk * 16;
    const size_t ho = (size_t)(b * Hq + h) * Sq * DHq;
    const bf16* Qh = Qg + ho;
    const bf16* Kh = Kg + ho;
    const bf16* Vh = Vtg + ho;           // [DH=64][S=1024]

    const bf16x8 aq0 = ld8(Qh + (size_t)(i_base + l16) * DHq + quad * 8);
    const bf16x8 aq1 = ld8(Qh + (size_t)(i_base + l16) * DHq + 32 + quad * 8);

    const int htype = (h < NCq) ? 0 : (h < NCq + NDq ? 1 : 2);
    float w = 0.f, dec = 0.f;
    if (htype == 0) {
        w = tdw[h];
        float xr = tdd[h];
        dec = (xr > 20.f) ? xr : log1pf(__expf(xr));   // softplus
    }
    const float* tvb = tv + b * Sq;
    float tvi[4];
    #pragma unroll
    for (int r = 0; r < 4; ++r) tvi[r] = (htype == 0) ? tvb[i_base + quad*4 + r] : 0.f;
    const unsigned int* mb = ((htype == 0) ? cb : db) + (size_t)b * (Sq * Sq / 32);

    f32x4 oacc[4];
    #pragma unroll
    for (int dt = 0; dt < 4; ++dt) { oacc[dt][0]=0.f; oacc[dt][1]=0.f; oacc[dt][2]=0.f; oacc[dt][3]=0.f; }
    float mrow[4] = {-1e30f, -1e30f, -1e30f, -1e30f};
    float lrow[4] = {0.f, 0.f, 0.f, 0.f};

    const int jend = (htype == 2) ? (i_base + 16) : Sq;

    // ---- prefetch step 0: K frags + mask words + key times ----
    bf16x8 bka[4], bkb[4];
    #pragma unroll
    for (int t = 0; t < 4; ++t) {
        bka[t] = ld8(Kh + (size_t)(t*16 + l16) * DHq + quad * 8);
        bkb[t] = ld8(Kh + (size_t)(t*16 + l16) * DHq + 32 + quad * 8);
    }
    uint2 mw[4]; float tj[4];
    if (htype < 2) {
        #pragma unroll
        for (int r = 0; r < 4; ++r)
            mw[r] = *(const uint2*)(mb + (((size_t)(i_base + quad*4 + r)) << 5));
    }
    if (htype == 0) {
        #pragma unroll
        for (int cc = 0; cc < 4; ++cc) tj[cc] = tvb[cc*16 + l16];
    }

    for (int j0 = 0; j0 < jend; j0 += 64) {
        // ---- QK^T on prefetched K frags ----
        f32x4 c[4];
        #pragma unroll
        for (int t = 0; t < 4; ++t) { c[t][0]=0.f; c[t][1]=0.f; c[t][2]=0.f; c[t][3]=0.f; }
        #pragma unroll
        for (int t = 0; t < 4; ++t) {
            c[t] = __builtin_amdgcn_mfma_f32_16x16x32_bf16(aq0, bka[t], c[t], 0, 0, 0);
            c[t] = __builtin_amdgcn_mfma_f32_16x16x32_bf16(aq1, bkb[t], c[t], 0, 0, 0);
        }

        // stash current-step operands, then issue next-step loads
        uint2 mwc[4]; float tjc[4];
        #pragma unroll
        for (int r = 0; r < 4; ++r) mwc[r] = mw[r];
        #pragma unroll
        for (int cc = 0; cc < 4; ++cc) tjc[cc] = tj[cc];

        const int jn = j0 + 64;
        if (jn < jend) {
            #pragma unroll
            for (int t = 0; t < 4; ++t) {
                bka[t] = ld8(Kh + (size_t)(jn + t*16 + l16) * DHq + quad * 8);
                bkb[t] = ld8(Kh + (size_t)(jn + t*16 + l16) * DHq + 32 + quad * 8);
            }
            if (htype < 2) {
                #pragma unroll
                for (int r = 0; r < 4; ++r)
                    mw[r] = *(const uint2*)(mb + (((size_t)(i_base + quad*4 + r)) << 5) + (jn >> 5));
            }
            if (htype == 0) {
                #pragma unroll
                for (int cc = 0; cc < 4; ++cc) tj[cc] = tvb[jn + cc*16 + l16];
            }
        }

        // ---- V frags for this step ----
        bf16x8 bv0[4], bv1[4];
        #pragma unroll
        for (int dt = 0; dt < 4; ++dt) {
            bv0[dt] = ld8(Vh + (size_t)(dt*16 + l16) * Sq + j0      + quad * 8);
            bv1[dt] = ld8(Vh + (size_t)(dt*16 + l16) * Sq + j0 + 32 + quad * 8);
        }

        // ---- online softmax (DPP reductions) ----
        float alpha[4];
        #pragma unroll
        for (int r = 0; r < 4; ++r) {
            const int i = i_base + quad*4 + r;
            float s[4];
            #pragma unroll
            for (int cc = 0; cc < 4; ++cc) s[cc] = c[cc][r];
            if (htype == 0) {
                #pragma unroll
                for (int cc = 0; cc < 4; ++cc) {
                    const unsigned int word = (cc < 2) ? mwc[r].x : mwc[r].y;
                    const int bit = (word >> (l16 + ((cc & 1) << 4))) & 1;
                    const float bias = w * __expf(-dec * fabsf(tvi[r] - tjc[cc]));
                    s[cc] = bit ? (s[cc] + bias) : -1e30f;
                }
            } else if (htype == 1) {
                #pragma unroll
                for (int cc = 0; cc < 4; ++cc) {
                    const unsigned int word = (cc < 2) ? mwc[r].x : mwc[r].y;
                    const int bit = (word >> (l16 + ((cc & 1) << 4))) & 1;
                    s[cc] = bit ? s[cc] : -1e30f;
                }
            } else {
                #pragma unroll
                for (int cc = 0; cc < 4; ++cc)
                    s[cc] = (j0 + cc*16 + l16 <= i) ? s[cc] : -1e30f;
            }
            float t = red16_max(fmaxf(fmaxf(s[0], s[1]), fmaxf(s[2], s[3])));
            const float mn = fmaxf(mrow[r], t);
            const float al = __expf(mrow[r] - mn);
            float p[4], rs = 0.f;
            #pragma unroll
            for (int cc = 0; cc < 4; ++cc) { p[cc] = __expf(s[cc] - mn); rs += p[cc]; }
            rs = red16_sum(rs);
            lrow[r] = lrow[r] * al + rs;
            mrow[r] = mn;
            alpha[r] = al;
            #pragma unroll
            for (int cc = 0; cc < 4; ++cc)
                Pt[quad*4 + r][cc*16 + l16] = f2bf(p[cc]);
        }

        __builtin_amdgcn_sched_barrier(0);   // pin ds_writes above ds_reads (wave-local DS pipe)

        union { uint4 u; bf16x8 v; } ap0, ap1;
        ap0.u = *(const uint4*)&Pt[l16][quad * 8];
        ap1.u = *(const uint4*)&Pt[l16][32 + quad * 8];

        // ---- PV ----
        #pragma unroll
        for (int dt = 0; dt < 4; ++dt) {
            #pragma unroll
            for (int r = 0; r < 4; ++r) oacc[dt][r] *= alpha[r];
            oacc[dt] = __builtin_amdgcn_mfma_f32_16x16x32_bf16(ap0.v, bv0[dt], oacc[dt], 0, 0, 0);
            oacc[dt] = __builtin_amdgcn_mfma_f32_16x16x32_bf16(ap1.v, bv1[dt], oacc[dt], 0, 0, 0);
        }
    }

    float inv[4];
    #pragma unroll
    for (int r = 0; r < 4; ++r) inv[r] = 1.f / lrow[r];
    #pragma unroll
    for (int dt = 0; dt < 4; ++dt) {
        #pragma unroll
        for (int r = 0; r < 4; ++r) {
            const int i = i_base + quad*4 + r;
            O[((size_t)(b * Sq + i)) * Dq + h * DHq + dt*16 + l16] =
                __float2bfloat16(oacc[dt][r] * inv[r]);
        }
    }
}

// ---------------- K3: output projection, MFMA 128x128 tile ----------------
__global__ __launch_bounds__(256, 3) void gemm_out_mfma(
    const bf16* __restrict__ A, const bf16* __restrict__ Wob,
    const float* __restrict__ bias, float* __restrict__ out)
{
    __shared__ __align__(16) char smem[16384];
    bf16* ldsA = (bf16*)smem;
    bf16* ldsB = (bf16*)(smem + 8192);

    const int tid  = threadIdx.x;
    const int wave = tid >> 6, lane = tid & 63;
    const int quad = lane >> 4, l16 = lane & 15;
    const int bm = blockIdx.x & 31;
    const int bn = blockIdx.x >> 5;
    const int m0 = bm * 128, n0 = bn * 128;
    const int wm = wave & 1, wn = wave >> 1;
    const int rA = lane >> 2, c8 = (lane & 3) * 8;
    const int cA0 = wave, cA1 = wave + 4;

    f32x4 acc[4][4];
    #pragma unroll
    for (int i = 0; i < 4; ++i)
        #pragma unroll
        for (int j = 0; j < 4; ++j) { acc[i][j][0]=0.f; acc[i][j][1]=0.f; acc[i][j][2]=0.f; acc[i][j][3]=0.f; }

    for (int k0 = 0; k0 < 1024; k0 += 32) {
        gload16(A   + (size_t)(m0 + cA0*16 + rA) * 1024 + k0 + c8, smem        + cA0*1024);
        gload16(A   + (size_t)(m0 + cA1*16 + rA) * 1024 + k0 + c8, smem        + cA1*1024);
        gload16(Wob + (size_t)(n0 + cA0*16 + rA) * 1024 + k0 + c8, smem + 8192 + cA0*1024);
        gload16(Wob + (size_t)(n0 + cA1*16 + rA) * 1024 + k0 + c8, smem + 8192 + cA1*1024);
        __syncthreads();
        bf16x8 af[4], bfr[4];
        #pragma unroll
        for (int i = 0; i < 4; ++i) af[i] = ld8(ldsA + (wm*64 + i*16 + l16) * 32 + quad*8);
        #pragma unroll
        for (int j = 0; j < 4; ++j) bfr[j] = ld8(ldsB + (wn*64 + j*16 + l16) * 32 + quad*8);
        #pragma unroll
        for (int i = 0; i < 4; ++i)
            #pragma unroll
            for (int j = 0; j < 4; ++j)
                acc[i][j] = __builtin_amdgcn_mfma_f32_16x16x32_bf16(af[i], bfr[j], acc[i][j], 0, 0, 0);
        __syncthreads();
    }

    const int nw = n0 + wn * 64;
    float bj[4];
    #pragma unroll
    for (int j = 0; j < 4; ++j) bj[j] = bias[nw + j*16 + l16];
    #pragma unroll
    for (int i = 0; i < 4; ++i) {
        #pragma unroll
        for (int r = 0; r < 4; ++r) {
            const int m = m0 + wm*64 + i*16 + quad*4 + r;
            #pragma unroll
            for (int j = 0; j < 4; ++j)
                out[(size_t)m * Dq + nw + j*16 + l16] = acc[i][j][r] + bj[j];
        }
    }
}

extern "C" void kernel_launch(void* const* d_in, const int* in_sizes, int n_in,
                              void* d_out, int out_size, void* d_ws, size_t ws_size,
                              hipStream_t stream)
{
    const float* x    = (const float*)d_in[0];
    const int*   caus = (const int*)d_in[1]; (void)caus;
    const int*   card = (const int*)d_in[2];
    const int*   deck = (const int*)d_in[3];
    const float* td   = (const float*)d_in[4];
    const float* ipw  = (const float*)d_in[5];
    const float* ipb  = (const float*)d_in[6];
    const float* opw  = (const float*)d_in[7];
    const float* opb  = (const float*)d_in[8];
    const float* tdw  = (const float*)d_in[9];
    const float* tdd  = (const float*)d_in[10];
    float* out = (float*)d_out;

    char* ws = (char*)d_ws;
    bf16* Q   = (bf16*)(ws);                              // 8 MB (B,H,S,DH) pre-scaled
    bf16* K   = (bf16*)(ws + (size_t)( 8u << 20));        // 8 MB (B,H,S,DH)
    bf16* Vt  = (bf16*)(ws + (size_t)(16u << 20));        // 8 MB (B,H,DH,S)
    bf16* O   = (bf16*)(ws + (size_t)(24u << 20));        // 8 MB (B,S,D)
    bf16* Xb  = (bf16*)(ws + (size_t)(32u << 20));        // 8 MB
    bf16* Wib = (bf16*)(ws + (size_t)(40u << 20));        // 6 MB
    bf16* Wob = (bf16*)(ws + (size_t)(46u << 20));        // 2 MB
    unsigned int* cbits = (unsigned int*)(ws + (size_t)(48u << 20));            // 512 KB
    unsigned int* dbits = (unsigned int*)(ws + (size_t)(48u << 20) + 524288);   // 512 KB
    float*        tvv   = (float*)(ws + (size_t)(48u << 20) + 1048576);         // 16 KB

    hipLaunchKernelGGL(prep_kernel, dim3(8192 + 16384), dim3(256), 0, stream,
                       x, Xb, ipw, Wib, opw, Wob, card, deck, td, cbits, dbits, tvv);
    hipLaunchKernelGGL(gemm_qkv_mfma, dim3(32 * 24), dim3(256), 0, stream,
                       Xb, Wib, ipb, Q, K, Vt);
    hipLaunchKernelGGL(attn_mfma4_kernel, dim3(Bq * Hq * (Sq / 16)), dim3(64), 0, stream,
                       Q, K, Vt, cbits, dbits, tvv, tdw, tdd, O);
    hipLaunchKernelGGL(gemm_out_mfma, dim3(32 * 8), dim3(256), 0, stream,
                       O, Wob, opb, out);
    (void)ws_size; (void)in_sizes; (void)n_in; (void)out_size;
}

// Round 8
// 311.845 us; speedup vs baseline: 1.2775x; 1.2775x over previous
//
#include <hip/hip_runtime.h>
#include <hip/hip_bf16.h>

typedef __hip_bfloat16 bf16;
typedef __bf16 bf16x8 __attribute__((ext_vector_type(8)));
typedef float  f32x4  __attribute__((ext_vector_type(4)));

#define Bq  4
#define Sq  1024
#define Dq  1024
#define Hq  16
#define DHq 64
#define NCq 8
#define NDq 4

__device__ __forceinline__ float bf2f(unsigned short u) {
    union { float f; unsigned int i; } x;
    x.i = ((unsigned int)u) << 16;
    return x.f;
}
__device__ __forceinline__ unsigned short f2bf(float f) {
    union { float f; unsigned int u; } x; x.f = f;
    unsigned int r = x.u + 0x7fffu + ((x.u >> 16) & 1u);
    return (unsigned short)(r >> 16);
}
__device__ __forceinline__ bf16x8 ld8(const bf16* p) {
    union { uint4 u; bf16x8 v; } t;
    t.u = *(const uint4*)p;
    return t.v;
}
__device__ __forceinline__ void gload16(const void* g, void* l) {
    __builtin_amdgcn_global_load_lds(
        (const __attribute__((address_space(1))) void*)g,
        (__attribute__((address_space(3))) void*)l, 16, 0, 0);
}

// ---- DPP 16-lane reductions (VALU-only, no LDS latency) ----
template<int C> __device__ __forceinline__ float dpp_f(float x) {
    return __int_as_float(__builtin_amdgcn_update_dpp(0, __float_as_int(x), C, 0xF, 0xF, true));
}
__device__ __forceinline__ float red16_max(float x) {
    x = fmaxf(x, dpp_f<0xB1>(x));    // quad_perm xor1
    x = fmaxf(x, dpp_f<0x4E>(x));    // quad_perm xor2
    x = fmaxf(x, dpp_f<0x141>(x));   // row_half_mirror
    x = fmaxf(x, dpp_f<0x140>(x));   // row_mirror
    return x;
}
__device__ __forceinline__ float red16_sum(float x) {
    x += dpp_f<0xB1>(x);
    x += dpp_f<0x4E>(x);
    x += dpp_f<0x141>(x);
    x += dpp_f<0x140>(x);
    return x;
}

// ---------------- K0: prep — fp32->bf16 converts + mask bit-pack + time vector ----------------
__global__ __launch_bounds__(256) void prep_kernel(
    const float* __restrict__ X,  bf16* __restrict__ Xb,
    const float* __restrict__ Wi, bf16* __restrict__ Wib,
    const float* __restrict__ Wo, bf16* __restrict__ Wob,
    const int* __restrict__ card, const int* __restrict__ deck,
    const float* __restrict__ td,
    unsigned int* __restrict__ cb, unsigned int* __restrict__ db,
    float* __restrict__ tv)
{
    const int blk = blockIdx.x;
    if (blk < 8192) {
        const float* src; bf16* dst; int base;
        if (blk < 4096)      { src = X;  dst = Xb;  base = blk; }
        else if (blk < 7168) { src = Wi; dst = Wib; base = blk - 4096; }
        else                 { src = Wo; dst = Wob; base = blk - 7168; }
        const size_t off = (size_t)base * 1024 + threadIdx.x * 4;
        float4 v = *(const float4*)(src + off);
        ushort4 o;
        o.x = f2bf(v.x); o.y = f2bf(v.y); o.z = f2bf(v.z); o.w = f2bf(v.w);
        *(ushort4*)(dst + off) = o;
    } else {
        const size_t idx = (size_t)(blk - 8192) * 256 + threadIdx.x;
        const bool c = card[idx] != 0;
        const bool d = deck[idx] != 0;
        unsigned long long bc = __ballot(c);
        unsigned long long bd = __ballot(d);
        const int lane = threadIdx.x & 63;
        if (lane == 0) {
            cb[idx >> 5] = (unsigned int)bc;
            db[idx >> 5] = (unsigned int)bd;
        } else if (lane == 32) {
            cb[idx >> 5] = (unsigned int)(bc >> 32);
            db[idx >> 5] = (unsigned int)(bd >> 32);
        }
        if (idx < (size_t)Bq * Sq)
            tv[idx] = td[idx * Sq];      // column 0 == t_s - t_0 (exact)
    }
}

// ---------------- K1: QKV projection, MFMA 128x128 tile ----------------
__global__ __launch_bounds__(256, 3) void gemm_qkv_mfma(
    const bf16* __restrict__ Xb, const bf16* __restrict__ Wib,
    const float* __restrict__ bias,
    bf16* __restrict__ Q, bf16* __restrict__ K, bf16* __restrict__ Vt)
{
    __shared__ __align__(16) char smem[36864];
    bf16* ldsA = (bf16*)smem;
    bf16* ldsB = (bf16*)(smem + 8192);

    const int tid  = threadIdx.x;
    const int wave = tid >> 6, lane = tid & 63;
    const int quad = lane >> 4, l16 = lane & 15;
    const int bm = blockIdx.x & 31;
    const int bn = blockIdx.x >> 5;
    const int m0 = bm * 128, n0 = bn * 128;
    const int wm = wave & 1, wn = wave >> 1;
    const int rA = lane >> 2, c8 = (lane & 3) * 8;
    const int cA0 = wave, cA1 = wave + 4;

    f32x4 acc[4][4];
    #pragma unroll
    for (int i = 0; i < 4; ++i)
        #pragma unroll
        for (int j = 0; j < 4; ++j) { acc[i][j][0]=0.f; acc[i][j][1]=0.f; acc[i][j][2]=0.f; acc[i][j][3]=0.f; }

    for (int k0 = 0; k0 < 1024; k0 += 32) {
        gload16(Xb  + (size_t)(m0 + cA0*16 + rA) * 1024 + k0 + c8, smem        + cA0*1024);
        gload16(Xb  + (size_t)(m0 + cA1*16 + rA) * 1024 + k0 + c8, smem        + cA1*1024);
        gload16(Wib + (size_t)(n0 + cA0*16 + rA) * 1024 + k0 + c8, smem + 8192 + cA0*1024);
        gload16(Wib + (size_t)(n0 + cA1*16 + rA) * 1024 + k0 + c8, smem + 8192 + cA1*1024);
        __syncthreads();
        bf16x8 af[4], bfr[4];
        #pragma unroll
        for (int i = 0; i < 4; ++i) af[i] = ld8(ldsA + (wm*64 + i*16 + l16) * 32 + quad*8);
        #pragma unroll
        for (int j = 0; j < 4; ++j) bfr[j] = ld8(ldsB + (wn*64 + j*16 + l16) * 32 + quad*8);
        #pragma unroll
        for (int i = 0; i < 4; ++i)
            #pragma unroll
            for (int j = 0; j < 4; ++j)
                acc[i][j] = __builtin_amdgcn_mfma_f32_16x16x32_bf16(af[i], bfr[j], acc[i][j], 0, 0, 0);
        __syncthreads();
    }

    const int nw  = n0 + wn * 64;
    const int sec = n0 >> 10;
    float bj[4];
    #pragma unroll
    for (int j = 0; j < 4; ++j) bj[j] = bias[nw + j*16 + l16];

    if (sec < 2) {
        #pragma unroll
        for (int i = 0; i < 4; ++i) {
            #pragma unroll
            for (int r = 0; r < 4; ++r) {
                const int m = m0 + wm*64 + i*16 + quad*4 + r;
                const int b = m >> 10, s = m & 1023;
                #pragma unroll
                for (int j = 0; j < 4; ++j) {
                    const int n = nw + j*16 + l16;
                    const int o = n & 1023;
                    const int h = o >> 6, dh = o & 63;
                    const float v = acc[i][j][r] + bj[j];
                    const size_t dst = (((size_t)(b * Hq + h)) * Sq + s) * DHq + dh;
                    if (sec == 0) Q[dst] = __float2bfloat16(v * 0.125f);
                    else          K[dst] = __float2bfloat16(v);
                }
            }
        }
    } else {
        unsigned short* Tr = (unsigned short*)(smem + wave * 9216);  // [64][72]
        #pragma unroll
        for (int i = 0; i < 4; ++i)
            #pragma unroll
            for (int j = 0; j < 4; ++j)
                #pragma unroll
                for (int r = 0; r < 4; ++r)
                    Tr[(j*16 + l16) * 72 + i*16 + quad*4 + r] = f2bf(acc[i][j][r] + bj[j]);
        __syncthreads();
        const int h  = (bn - 16) * 2 + wn;
        const int bB = m0 >> 10;
        const int s0 = (m0 & 1023) + wm * 64;
        const int r8 = lane >> 3, c16 = lane & 7;
        #pragma unroll
        for (int it = 0; it < 8; ++it) {
            const int dh = it * 8 + r8;
            uint4 u = *(const uint4*)(Tr + dh * 72 + c16 * 8);
            *(uint4*)(Vt + ((size_t)(bB * Hq + h) * DHq + dh) * Sq + s0 + c16 * 8) = u;
        }
    }
}

// ---------------- K2: MFMA flash attention — single-wave blocks, no spill ----------------
// Grid: B*H*(S/16) = 4096 blocks of 64 threads; one wave owns 16 query rows.
// launch_bounds(64,3): 170-reg cap (live set ~105) -> no scratch, 12 waves/CU.
__global__ __launch_bounds__(64, 3) void attn_mfma5_kernel(
    const bf16* __restrict__ Qg, const bf16* __restrict__ Kg, const bf16* __restrict__ Vtg,
    const unsigned int* __restrict__ cb, const unsigned int* __restrict__ db,
    const float* __restrict__ tv,
    const float* __restrict__ tdw, const float* __restrict__ tdd,
    bf16* __restrict__ O)
{
    __shared__ unsigned short Pt[16][72];
    const int lane = threadIdx.x & 63;
    const int quad = lane >> 4, l16 = lane & 15;
    const int blk  = blockIdx.x;
    // swizzle: chunk slow -> all chunks of one (b,h) share blk&7 (same XCD)
    const int chunk = blk >> 6;          // 0..63 (16-row chunks)
    const int h     = (blk >> 2) & 15;
    const int b     = blk & 3;
    const int i_base = chunk * 16;
    const size_t ho = (size_t)(b * Hq + h) * Sq * DHq;
    const bf16* Qh = Qg + ho;
    const bf16* Kh = Kg + ho;
    const bf16* Vh = Vtg + ho;           // [DH=64][S=1024]

    const bf16x8 aq0 = ld8(Qh + (size_t)(i_base + l16) * DHq + quad * 8);
    const bf16x8 aq1 = ld8(Qh + (size_t)(i_base + l16) * DHq + 32 + quad * 8);

    const int htype = (h < NCq) ? 0 : (h < NCq + NDq ? 1 : 2);
    float w = 0.f, dec = 0.f;
    if (htype == 0) {
        w = tdw[h];
        float xr = tdd[h];
        dec = (xr > 20.f) ? xr : log1pf(__expf(xr));   // softplus
    }
    const float* tvb = tv + b * Sq;
    float tvi[4];
    #pragma unroll
    for (int r = 0; r < 4; ++r) tvi[r] = (htype == 0) ? tvb[i_base + quad*4 + r] : 0.f;
    const unsigned int* mb = ((htype == 0) ? cb : db) + (size_t)b * (Sq * Sq / 32);

    f32x4 oacc[4];
    #pragma unroll
    for (int dt = 0; dt < 4; ++dt) { oacc[dt][0]=0.f; oacc[dt][1]=0.f; oacc[dt][2]=0.f; oacc[dt][3]=0.f; }
    float mrow[4] = {-1e30f, -1e30f, -1e30f, -1e30f};
    float lrow[4] = {0.f, 0.f, 0.f, 0.f};

    const int jend = (htype == 2) ? (i_base + 16) : Sq;

    for (int j0 = 0; j0 < jend; j0 += 64) {
        // ---- K frags + QK^T (K frags die at end of this block) ----
        f32x4 c[4];
        {
            bf16x8 bka[4], bkb[4];
            #pragma unroll
            for (int t = 0; t < 4; ++t) {
                bka[t] = ld8(Kh + (size_t)(j0 + t*16 + l16) * DHq + quad * 8);
                bkb[t] = ld8(Kh + (size_t)(j0 + t*16 + l16) * DHq + 32 + quad * 8);
            }
            #pragma unroll
            for (int t = 0; t < 4; ++t) { c[t][0]=0.f; c[t][1]=0.f; c[t][2]=0.f; c[t][3]=0.f; }
            #pragma unroll
            for (int t = 0; t < 4; ++t) {
                c[t] = __builtin_amdgcn_mfma_f32_16x16x32_bf16(aq0, bka[t], c[t], 0, 0, 0);
                c[t] = __builtin_amdgcn_mfma_f32_16x16x32_bf16(aq1, bkb[t], c[t], 0, 0, 0);
            }
        }

        // ---- V frags issue now, consumed after softmax (overlap) ----
        bf16x8 bv0[4], bv1[4];
        #pragma unroll
        for (int dt = 0; dt < 4; ++dt) {
            bv0[dt] = ld8(Vh + (size_t)(dt*16 + l16) * Sq + j0      + quad * 8);
            bv1[dt] = ld8(Vh + (size_t)(dt*16 + l16) * Sq + j0 + 32 + quad * 8);
        }

        // ---- mask words + key times ----
        uint2 mw[4]; float tj[4];
        if (htype < 2) {
            #pragma unroll
            for (int r = 0; r < 4; ++r)
                mw[r] = *(const uint2*)(mb + (((size_t)(i_base + quad*4 + r)) << 5) + (j0 >> 5));
        }
        if (htype == 0) {
            #pragma unroll
            for (int cc = 0; cc < 4; ++cc) tj[cc] = tvb[j0 + cc*16 + l16];
        }

        // ---- online softmax (DPP reductions) ----
        float alpha[4];
        #pragma unroll
        for (int r = 0; r < 4; ++r) {
            const int i = i_base + quad*4 + r;
            float s[4];
            #pragma unroll
            for (int cc = 0; cc < 4; ++cc) s[cc] = c[cc][r];
            if (htype == 0) {
                #pragma unroll
                for (int cc = 0; cc < 4; ++cc) {
                    const unsigned int word = (cc < 2) ? mw[r].x : mw[r].y;
                    const int bit = (word >> (l16 + ((cc & 1) << 4))) & 1;
                    const float bias = w * __expf(-dec * fabsf(tvi[r] - tj[cc]));
                    s[cc] = bit ? (s[cc] + bias) : -1e30f;
                }
            } else if (htype == 1) {
                #pragma unroll
                for (int cc = 0; cc < 4; ++cc) {
                    const unsigned int word = (cc < 2) ? mw[r].x : mw[r].y;
                    const int bit = (word >> (l16 + ((cc & 1) << 4))) & 1;
                    s[cc] = bit ? s[cc] : -1e30f;
                }
            } else {
                #pragma unroll
                for (int cc = 0; cc < 4; ++cc)
                    s[cc] = (j0 + cc*16 + l16 <= i) ? s[cc] : -1e30f;
            }
            float t = red16_max(fmaxf(fmaxf(s[0], s[1]), fmaxf(s[2], s[3])));
            const float mn = fmaxf(mrow[r], t);
            const float al = __expf(mrow[r] - mn);
            float p[4], rs = 0.f;
            #pragma unroll
            for (int cc = 0; cc < 4; ++cc) { p[cc] = __expf(s[cc] - mn); rs += p[cc]; }
            rs = red16_sum(rs);
            lrow[r] = lrow[r] * al + rs;
            mrow[r] = mn;
            alpha[r] = al;
            #pragma unroll
            for (int cc = 0; cc < 4; ++cc)
                Pt[quad*4 + r][cc*16 + l16] = f2bf(p[cc]);
        }

        __builtin_amdgcn_sched_barrier(0);   // pin ds_writes above ds_reads (wave-local DS pipe)

        union { uint4 u; bf16x8 v; } ap0, ap1;
        ap0.u = *(const uint4*)&Pt[l16][quad * 8];
        ap1.u = *(const uint4*)&Pt[l16][32 + quad * 8];

        // ---- PV ----
        #pragma unroll
        for (int dt = 0; dt < 4; ++dt) {
            #pragma unroll
            for (int r = 0; r < 4; ++r) oacc[dt][r] *= alpha[r];
            oacc[dt] = __builtin_amdgcn_mfma_f32_16x16x32_bf16(ap0.v, bv0[dt], oacc[dt], 0, 0, 0);
            oacc[dt] = __builtin_amdgcn_mfma_f32_16x16x32_bf16(ap1.v, bv1[dt], oacc[dt], 0, 0, 0);
        }
    }

    float inv[4];
    #pragma unroll
    for (int r = 0; r < 4; ++r) inv[r] = 1.f / lrow[r];
    #pragma unroll
    for (int dt = 0; dt < 4; ++dt) {
        #pragma unroll
        for (int r = 0; r < 4; ++r) {
            const int i = i_base + quad*4 + r;
            O[((size_t)(b * Sq + i)) * Dq + h * DHq + dt*16 + l16] =
                __float2bfloat16(oacc[dt][r] * inv[r]);
        }
    }
}

// ---------------- K3: output projection, MFMA 128x128 tile ----------------
__global__ __launch_bounds__(256, 3) void gemm_out_mfma(
    const bf16* __restrict__ A, const bf16* __restrict__ Wob,
    const float* __restrict__ bias, float* __restrict__ out)
{
    __shared__ __align__(16) char smem[16384];
    bf16* ldsA = (bf16*)smem;
    bf16* ldsB = (bf16*)(smem + 8192);

    const int tid  = threadIdx.x;
    const int wave = tid >> 6, lane = tid & 63;
    const int quad = lane >> 4, l16 = lane & 15;
    const int bm = blockIdx.x & 31;
    const int bn = blockIdx.x >> 5;
    const int m0 = bm * 128, n0 = bn * 128;
    const int wm = wave & 1, wn = wave >> 1;
    const int rA = lane >> 2, c8 = (lane & 3) * 8;
    const int cA0 = wave, cA1 = wave + 4;

    f32x4 acc[4][4];
    #pragma unroll
    for (int i = 0; i < 4; ++i)
        #pragma unroll
        for (int j = 0; j < 4; ++j) { acc[i][j][0]=0.f; acc[i][j][1]=0.f; acc[i][j][2]=0.f; acc[i][j][3]=0.f; }

    for (int k0 = 0; k0 < 1024; k0 += 32) {
        gload16(A   + (size_t)(m0 + cA0*16 + rA) * 1024 + k0 + c8, smem        + cA0*1024);
        gload16(A   + (size_t)(m0 + cA1*16 + rA) * 1024 + k0 + c8, smem        + cA1*1024);
        gload16(Wob + (size_t)(n0 + cA0*16 + rA) * 1024 + k0 + c8, smem + 8192 + cA0*1024);
        gload16(Wob + (size_t)(n0 + cA1*16 + rA) * 1024 + k0 + c8, smem + 8192 + cA1*1024);
        __syncthreads();
        bf16x8 af[4], bfr[4];
        #pragma unroll
        for (int i = 0; i < 4; ++i) af[i] = ld8(ldsA + (wm*64 + i*16 + l16) * 32 + quad*8);
        #pragma unroll
        for (int j = 0; j < 4; ++j) bfr[j] = ld8(ldsB + (wn*64 + j*16 + l16) * 32 + quad*8);
        #pragma unroll
        for (int i = 0; i < 4; ++i)
            #pragma unroll
            for (int j = 0; j < 4; ++j)
                acc[i][j] = __builtin_amdgcn_mfma_f32_16x16x32_bf16(af[i], bfr[j], acc[i][j], 0, 0, 0);
        __syncthreads();
    }

    const int nw = n0 + wn * 64;
    float bj[4];
    #pragma unroll
    for (int j = 0; j < 4; ++j) bj[j] = bias[nw + j*16 + l16];
    #pragma unroll
    for (int i = 0; i < 4; ++i) {
        #pragma unroll
        for (int r = 0; r < 4; ++r) {
            const int m = m0 + wm*64 + i*16 + quad*4 + r;
            #pragma unroll
            for (int j = 0; j < 4; ++j)
                out[(size_t)m * Dq + nw + j*16 + l16] = acc[i][j][r] + bj[j];
        }
    }
}

extern "C" void kernel_launch(void* const* d_in, const int* in_sizes, int n_in,
                              void* d_out, int out_size, void* d_ws, size_t ws_size,
                              hipStream_t stream)
{
    const float* x    = (const float*)d_in[0];
    const int*   caus = (const int*)d_in[1]; (void)caus;
    const int*   card = (const int*)d_in[2];
    const int*   deck = (const int*)d_in[3];
    const float* td   = (const float*)d_in[4];
    const float* ipw  = (const float*)d_in[5];
    const float* ipb  = (const float*)d_in[6];
    const float* opw  = (const float*)d_in[7];
    const float* opb  = (const float*)d_in[8];
    const float* tdw  = (const float*)d_in[9];
    const float* tdd  = (const float*)d_in[10];
    float* out = (float*)d_out;

    char* ws = (char*)d_ws;
    bf16* Q   = (bf16*)(ws);                              // 8 MB (B,H,S,DH) pre-scaled
    bf16* K   = (bf16*)(ws + (size_t)( 8u << 20));        // 8 MB (B,H,S,DH)
    bf16* Vt  = (bf16*)(ws + (size_t)(16u << 20));        // 8 MB (B,H,DH,S)
    bf16* O   = (bf16*)(ws + (size_t)(24u << 20));        // 8 MB (B,S,D)
    bf16* Xb  = (bf16*)(ws + (size_t)(32u << 20));        // 8 MB
    bf16* Wib = (bf16*)(ws + (size_t)(40u << 20));        // 6 MB
    bf16* Wob = (bf16*)(ws + (size_t)(46u << 20));        // 2 MB
    unsigned int* cbits = (unsigned int*)(ws + (size_t)(48u << 20));            // 512 KB
    unsigned int* dbits = (unsigned int*)(ws + (size_t)(48u << 20) + 524288);   // 512 KB
    float*        tvv   = (float*)(ws + (size_t)(48u << 20) + 1048576);         // 16 KB

    hipLaunchKernelGGL(prep_kernel, dim3(8192 + 16384), dim3(256), 0, stream,
                       x, Xb, ipw, Wib, opw, Wob, card, deck, td, cbits, dbits, tvv);
    hipLaunchKernelGGL(gemm_qkv_mfma, dim3(32 * 24), dim3(256), 0, stream,
                       Xb, Wib, ipb, Q, K, Vt);
    hipLaunchKernelGGL(attn_mfma5_kernel, dim3(Bq * Hq * (Sq / 16)), dim3(64), 0, stream,
                       Q, K, Vt, cbits, dbits, tvv, tdw, tdd, O);
    hipLaunchKernelGGL(gemm_out_mfma, dim3(32 * 8), dim3(256), 0, stream,
                       O, Wob, opb, out);
    (void)ws_size; (void)in_sizes; (void)n_in; (void)out_size;
}